// Round 3
// baseline (515.261 us; speedup 1.0000x reference)
//
#include <hip/hip_runtime.h>

#define FV 128
#define NCLIN 38
#define NPIX 36
#define NTOT 74     // NCLIN + NPIX
#define BATCH 1024
#define HID 512
#define COMB 4992   // 39*128
#define XPAD 136    // LDS row stride in ushorts
#define NBLK 1024   // 4 blocks/CU co-resident (LDS 32KB, VGPR<=128 via launch_bounds)

typedef __attribute__((ext_vector_type(4))) float f32x4;
typedef __attribute__((ext_vector_type(8))) short s16x8;

// ws layout (float offsets):
//   WcT bf16 [0, 8192)           (W_self + W_msg/37)^T, [n][k]
//   WiT bf16 [8192, 16384)       (W_self + W_msg/39)^T
//   WmT bf16 [16384, 24576)      W_msg^T  (for t-vector MFMA)
//   combined [24576, 2580480)    bf16 (1024 x 4992)
//   W1T      [2580480, 3858432)  bf16 (512 x 4992)
//   z[8]     [3858432, 8052736)  fp32 partials, 8 x (1024 x 512)
//   bar      [8052736, +128 ints) barrier counters, 128B-spaced (k_init zeroes)
#define WS_WCT  0
#define WS_WIT  8192
#define WS_WMT  16384
#define WS_COMB 24576
#define WS_W1T  2580480
#define WS_Z    3858432
#define WS_BAR  8052736
#define ZSTRIDE (BATCH * HID)

__device__ __forceinline__ unsigned short bf16_rne(float f) {
    union { float f; unsigned int u; } v; v.f = f;
    unsigned int u = v.u;
    u += 0x7fffu + ((u >> 16) & 1u);
    return (unsigned short)(u >> 16);
}
__device__ __forceinline__ float bf2f(unsigned short h) {
    union { unsigned int u; float f; } v; v.u = ((unsigned int)h) << 16;
    return v.f;
}

// Device-wide barrier, latency-friendly version:
//  - one release fence + one RELAXED add on arrival
//  - RELAXED polls (no per-poll cache invalidation!) with s_sleep backoff
//  - one acquire fence after the count reaches NBLK
// Fence->atomic-write ... atomic-read->fence gives happens-before (C++ fences).
__device__ __forceinline__ void gbar(int* bar, int idx) {
    __syncthreads();
    if (threadIdx.x == 0) {
        __threadfence();  // release: prior global writes visible at agent scope
        __hip_atomic_fetch_add(&bar[idx * 32], 1,
                               __ATOMIC_RELAXED, __HIP_MEMORY_SCOPE_AGENT);
        while (__hip_atomic_load(&bar[idx * 32],
                                 __ATOMIC_RELAXED, __HIP_MEMORY_SCOPE_AGENT) < NBLK) {
            __builtin_amdgcn_s_sleep(8);
        }
        __threadfence();  // acquire: invalidate stale caches ONCE
    }
    __syncthreads();
}

// Zero the barrier words each graph replay (ws is poisoned between iterations).
__global__ void k_init(float* __restrict__ ws) {
    int* bar = (int*)(ws + WS_BAR);
    if (threadIdx.x < 128) bar[threadIdx.x] = 0;
}

union __align__(16) Smem {
    float tile[64][65];                        // phase B1: W1 transpose staging
    struct {
        unsigned short xl[NTOT * XPAD];
        unsigned short sab[2 * 128];
        float tcv[128];
        float tiv[128];
    } b;                                       // phase B2: per-batch pipeline
    struct {
        unsigned short As[2][4096];            // 2 x 8 KB
        unsigned short Bs[2][4096];            // 2 x 8 KB
    } c;                                       // phase C: gemm double buffer
    float dred[8];                             // phase D: block reduction
};

__global__ __launch_bounds__(256, 4) void k_fused(
    const float* __restrict__ clin, const float* __restrict__ img,
    const float* __restrict__ wself, const float* __restrict__ wmsg,
    const float* __restrict__ bg, const float* __restrict__ W1,
    const float* __restrict__ b1, const float* __restrict__ W2,
    const float* __restrict__ b2, float* __restrict__ ws,
    float* __restrict__ out)
{
    const int blk = blockIdx.x;
    const int t   = threadIdx.x;
    int* bar = (int*)(ws + WS_BAR);

    __shared__ Smem sm;

    // ================= Phase A: W-table prep (blocks 0..7) =================
    if (blk < 8) {
        unsigned short* WcT = (unsigned short*)(ws + WS_WCT);
        unsigned short* WiT = (unsigned short*)(ws + WS_WIT);
        unsigned short* WmT = (unsigned short*)(ws + WS_WMT);
        const int r  = blk * 16 + (t >> 4);
        const int f0 = (t & 15) * 8;
#pragma unroll
        for (int j = 0; j < 8; ++j) {
            const int f = f0 + j;
            const int idx = r * 128 + f;
            const float wm = wmsg[idx];
            const float s  = wself[idx];
            WcT[f * 128 + r] = bf16_rne(s + wm * (1.0f / 37.0f));
            WiT[f * 128 + r] = bf16_rne(s + wm * (1.0f / 39.0f));
            WmT[f * 128 + r] = bf16_rne(wm);
        }
    }

    // ================= Phase B1: W1 -> W1T bf16 transpose (624 blocks) =====
    if (blk < 624) {
        unsigned short* W1T = (unsigned short*)(ws + WS_W1T);
        const int k0 = (blk >> 3) * 64;   // 0..77 -> k tile
        const int n0 = (blk & 7) * 64;    // 0..7  -> n tile
        const int r16 = t >> 4;
        const int c4  = (t & 15) * 4;
#pragma unroll
        for (int p = 0; p < 4; ++p) {
            const int r = p * 16 + r16;
            const float4 v = *(const float4*)&W1[(size_t)(k0 + r) * HID + n0 + c4];
            sm.tile[r][c4 + 0] = v.x; sm.tile[r][c4 + 1] = v.y;
            sm.tile[r][c4 + 2] = v.z; sm.tile[r][c4 + 3] = v.w;
        }
        __syncthreads();
        const int j  = t >> 2;
        const int i0 = (t & 3) * 16;
        unsigned short tmp[16];
#pragma unroll
        for (int s = 0; s < 16; ++s) tmp[s] = bf16_rne(sm.tile[i0 + s][j]);
        unsigned short* dst = &W1T[(size_t)(n0 + j) * COMB + k0 + i0];
        *(uint4*)&dst[0] = *(uint4*)&tmp[0];
        *(uint4*)&dst[8] = *(uint4*)&tmp[8];
        __syncthreads();  // LDS overlay reused below
    }
    gbar(bar, 0);

    // ================= Phase B2: per-batch pipeline (1 batch per block) ====
    {
        const unsigned short* WcT = (const unsigned short*)(ws + WS_WCT);
        const unsigned short* WiT = (const unsigned short*)(ws + WS_WIT);
        const unsigned short* WmT = (const unsigned short*)(ws + WS_WMT);
        const int wave = t >> 6;
        const int lane = t & 63;
        const int l16  = lane & 15;
        const int q    = lane >> 4;
        const int n0   = wave * 32 + l16;
        const int b    = blk;

        // ---- stage x as bf16 ----
        const float* xc = clin + (size_t)b * NCLIN * FV;
        const float* xi = img  + (size_t)b * NPIX * FV;
        for (int i = t; i < NCLIN * 32; i += 256) {
            const int row = i >> 5, c4 = (i & 31) * 4;
            const float4 v = *(const float4*)&xc[row * 128 + c4];
            ushort4 u;
            u.x = bf16_rne(v.x); u.y = bf16_rne(v.y);
            u.z = bf16_rne(v.z); u.w = bf16_rne(v.w);
            *(ushort4*)&sm.b.xl[row * XPAD + c4] = u;
        }
        for (int i = t; i < NPIX * 32; i += 256) {
            const int row = i >> 5, c4 = (i & 31) * 4;
            const float4 v = *(const float4*)&xi[row * 128 + c4];
            ushort4 u;
            u.x = bf16_rne(v.x); u.y = bf16_rne(v.y);
            u.z = bf16_rne(v.z); u.w = bf16_rne(v.w);
            *(ushort4*)&sm.b.xl[(NCLIN + row) * XPAD + c4] = u;
        }
        __syncthreads();

        // ---- feature sums -> sab (bf16) ----
        const int f = t & 127;
        if (t < 128) {
            float s = 0.f;
#pragma unroll
            for (int n = 0; n < NCLIN; ++n) s += bf2f(sm.b.xl[n * XPAD + f]);
            sm.b.sab[128 + f] = bf16_rne(s * (1.0f / 39.0f));
        } else {
            float s = 0.f;
#pragma unroll
            for (int n = 0; n < NPIX; ++n) s += bf2f(sm.b.xl[(NCLIN + n) * XPAD + f]);
            sm.b.sab[f] = bf16_rne(s * (1.0f / 37.0f));
        }
        __syncthreads();

        // ---- t vectors via MFMA ----
        {
            const int am = (l16 < 2) ? l16 : 0;
            f32x4 ta = {}, tb = {};
#pragma unroll
            for (int kk = 0; kk < 4; ++kk) {
                const int ko = kk * 32 + q * 8;
                const s16x8 av  = *(const s16x8*)&sm.b.sab[am * 128 + ko];
                const s16x8 bv0 = *(const s16x8*)&WmT[(n0)      * 128 + ko];
                const s16x8 bv1 = *(const s16x8*)&WmT[(n0 + 16) * 128 + ko];
                ta = __builtin_amdgcn_mfma_f32_16x16x32_bf16(av, bv0, ta, 0, 0, 0);
                tb = __builtin_amdgcn_mfma_f32_16x16x32_bf16(av, bv1, tb, 0, 0, 0);
            }
            if (q == 0) {
                const int c0 = wave * 32 + l16;
                const int c1 = c0 + 16;
                const float bg0 = bg[c0], bg1 = bg[c1];
                sm.b.tcv[c0] = ta[0] + bg0;  sm.b.tiv[c0] = ta[1] + bg0;
                sm.b.tcv[c1] = tb[0] + bg1;  sm.b.tiv[c1] = tb[1] + bg1;
            }
        }
        __syncthreads();

        // ---- MFMA node transform, both phases ----
        unsigned short* combined =
            (unsigned short*)(ws + WS_COMB) + (size_t)b * COMB;

#pragma unroll
        for (int phase = 0; phase < 2; ++phase) {
            const int NN   = phase ? NPIX : NCLIN;
            const int xoff = phase ? NCLIN : 0;
            const unsigned short* WT = phase ? WiT : WcT;
            const float* tvv = phase ? sm.b.tiv : sm.b.tcv;

            const int r0 = xoff + ((l16      < NN) ? l16      : (NN - 1));
            const int r1 = xoff + ((16 + l16 < NN) ? 16 + l16 : (NN - 1));
            const int r2 = xoff + ((32 + l16 < NN) ? 32 + l16 : (NN - 1));

            f32x4 acc[3][2] = {};
#pragma unroll
            for (int kk = 0; kk < 4; ++kk) {
                const int ko = kk * 32 + q * 8;
                const s16x8 a0 = *(const s16x8*)&sm.b.xl[r0 * XPAD + ko];
                const s16x8 a1 = *(const s16x8*)&sm.b.xl[r1 * XPAD + ko];
                const s16x8 a2 = *(const s16x8*)&sm.b.xl[r2 * XPAD + ko];
                const s16x8 b0 = *(const s16x8*)&WT[(n0)      * 128 + ko];
                const s16x8 b1v = *(const s16x8*)&WT[(n0 + 16) * 128 + ko];
                acc[0][0] = __builtin_amdgcn_mfma_f32_16x16x32_bf16(a0, b0,  acc[0][0], 0, 0, 0);
                acc[0][1] = __builtin_amdgcn_mfma_f32_16x16x32_bf16(a0, b1v, acc[0][1], 0, 0, 0);
                acc[1][0] = __builtin_amdgcn_mfma_f32_16x16x32_bf16(a1, b0,  acc[1][0], 0, 0, 0);
                acc[1][1] = __builtin_amdgcn_mfma_f32_16x16x32_bf16(a1, b1v, acc[1][1], 0, 0, 0);
                acc[2][0] = __builtin_amdgcn_mfma_f32_16x16x32_bf16(a2, b0,  acc[2][0], 0, 0, 0);
                acc[2][1] = __builtin_amdgcn_mfma_f32_16x16x32_bf16(a2, b1v, acc[2][1], 0, 0, 0);
            }

            const float t0 = tvv[wave * 32 + l16];
            const float t1 = tvv[wave * 32 + 16 + l16];

            if (phase == 0) {
#pragma unroll
                for (int rt = 0; rt < 3; ++rt) {
#pragma unroll
                    for (int r = 0; r < 4; ++r) {
                        const int node = rt * 16 + q * 4 + r;
                        if (node < NCLIN) {
                            combined[node * 128 + wave * 32 + l16] =
                                bf16_rne(fmaxf(acc[rt][0][r] + t0, 0.f));
                            combined[node * 128 + wave * 32 + 16 + l16] =
                                bf16_rne(fmaxf(acc[rt][1][r] + t1, 0.f));
                        }
                    }
                }
            } else {
                float g0 = 0.f, g1 = 0.f;
#pragma unroll
                for (int rt = 0; rt < 3; ++rt) {
#pragma unroll
                    for (int r = 0; r < 4; ++r) {
                        const int node = rt * 16 + q * 4 + r;
                        if (node < NPIX) {
                            g0 += fmaxf(acc[rt][0][r] + t0, 0.f);
                            g1 += fmaxf(acc[rt][1][r] + t1, 0.f);
                        }
                    }
                }
                g0 += __shfl_xor(g0, 16); g0 += __shfl_xor(g0, 32);
                g1 += __shfl_xor(g1, 16); g1 += __shfl_xor(g1, 32);
                if (q == 0) {
                    combined[NCLIN * 128 + wave * 32 + l16] =
                        bf16_rne(g0 * (1.0f / 36.0f));
                    combined[NCLIN * 128 + wave * 32 + 16 + l16] =
                        bf16_rne(g1 * (1.0f / 36.0f));
                }
            }
        }
    }
    gbar(bar, 1);

    // ================= Phase C: split-K GEMM (256 active, spread 1/CU) =====
    if ((blk & 3) == 0) {
        const int cblk = blk >> 2;   // 0..255
        const unsigned short* Abase = (const unsigned short*)(ws + WS_COMB);
        const unsigned short* Bbase = (const unsigned short*)(ws + WS_W1T);
        const int m0    = (cblk & 7) * 128;
        const int n0    = ((cblk >> 3) & 3) * 128;
        const int ks    = cblk >> 5;
        const int kbase = (ks < 4) ? 640 * ks : 2560 + 608 * (ks - 4);
        const int kit   = (ks < 4) ? 20 : 19;
        float* Z = ws + WS_Z + (size_t)ks * ZSTRIDE;

        const int wave = t >> 6;
        const int lane = t & 63;
        const int wm   = (wave & 1) * 64;
        const int wn   = (wave >> 1) * 64;
        const int l16  = lane & 15;
        const int q    = lane >> 4;

        const int srow = t >> 1;
        const int qb   = (t & 1) * 2;
        const unsigned short* gA = Abase + (size_t)(m0 + srow) * COMB + kbase + qb * 8;
        const unsigned short* gB = Bbase + (size_t)(n0 + srow) * COMB + kbase + qb * 8;
        const int sw0 = srow * 32 + ((qb     + (srow >> 1)) & 3) * 8;
        const int sw1 = srow * 32 + ((qb + 1 + (srow >> 1)) & 3) * 8;

        int aoff[4], boff[4];
#pragma unroll
        for (int i = 0; i < 4; ++i) {
            const int Ra = wm + i * 16 + l16;
            aoff[i] = Ra * 32 + ((q + (Ra >> 1)) & 3) * 8;
            const int Rb = wn + i * 16 + l16;
            boff[i] = Rb * 32 + ((q + (Rb >> 1)) & 3) * 8;
        }

        f32x4 acc[4][4] = {};

        *(uint4*)&sm.c.As[0][sw0] = *(const uint4*)(gA);
        *(uint4*)&sm.c.As[0][sw1] = *(const uint4*)(gA + 8);
        *(uint4*)&sm.c.Bs[0][sw0] = *(const uint4*)(gB);
        *(uint4*)&sm.c.Bs[0][sw1] = *(const uint4*)(gB + 8);

        int cur = 0;
        for (int it = 0; it < kit; ++it) {
            __syncthreads();
            if (it + 1 < kit) {
                const int kk  = (it + 1) * 32;
                const int nxt = cur ^ 1;
                *(uint4*)&sm.c.As[nxt][sw0] = *(const uint4*)(gA + kk);
                *(uint4*)&sm.c.As[nxt][sw1] = *(const uint4*)(gA + kk + 8);
                *(uint4*)&sm.c.Bs[nxt][sw0] = *(const uint4*)(gB + kk);
                *(uint4*)&sm.c.Bs[nxt][sw1] = *(const uint4*)(gB + kk + 8);
            }

            s16x8 af[4], bfr[4];
#pragma unroll
            for (int i = 0; i < 4; ++i) af[i]  = *(const s16x8*)&sm.c.As[cur][aoff[i]];
#pragma unroll
            for (int i = 0; i < 4; ++i) bfr[i] = *(const s16x8*)&sm.c.Bs[cur][boff[i]];

#pragma unroll
            for (int i = 0; i < 4; ++i) {
#pragma unroll
                for (int j = 0; j < 4; ++j) {
                    acc[i][j] = __builtin_amdgcn_mfma_f32_16x16x32_bf16(
                        af[i], bfr[j], acc[i][j], 0, 0, 0);
                }
            }
            cur ^= 1;
        }

#pragma unroll
        for (int i = 0; i < 4; ++i) {
#pragma unroll
            for (int r = 0; r < 4; ++r) {
                const int mr = m0 + wm + 16 * i + q * 4 + r;
                float* zr = Z + (size_t)mr * HID + n0 + wn + l16;
#pragma unroll
                for (int j = 0; j < 4; ++j) {
                    zr[16 * j] = acc[i][j][r];
                }
            }
        }
    }
    gbar(bar, 2);

    // ================= Phase D: output head (1 batch per block) ============
    {
        const int b = blk;
        const float* z = ws + WS_Z + (size_t)b * HID;
        float s = 0.f;
#pragma unroll
        for (int j = 0; j < 2; ++j) {
            const int h = t + j * 256;
            float acc = b1[h];
#pragma unroll
            for (int p = 0; p < 8; ++p) acc += z[(size_t)p * ZSTRIDE + h];
            s += fmaxf(acc, 0.f) * W2[h];
        }
#pragma unroll
        for (int off = 32; off > 0; off >>= 1) s += __shfl_down(s, off);
        if ((t & 63) == 0) sm.dred[t >> 6] = s;
        __syncthreads();
        if (t == 0) out[b] = sm.dred[0] + sm.dred[1] + sm.dred[2] + sm.dred[3] + b2[0];
    }
}

extern "C" void kernel_launch(void* const* d_in, const int* in_sizes, int n_in,
                              void* d_out, int out_size, void* d_ws, size_t ws_size,
                              hipStream_t stream) {
    const float* clin  = (const float*)d_in[0];
    const float* img   = (const float*)d_in[1];
    const float* wself = (const float*)d_in[2];
    const float* wmsg  = (const float*)d_in[3];
    const float* bg    = (const float*)d_in[4];
    const float* W1    = (const float*)d_in[5];
    const float* b1    = (const float*)d_in[6];
    const float* W2    = (const float*)d_in[7];
    const float* b2    = (const float*)d_in[8];
    float* ws  = (float*)d_ws;
    float* out = (float*)d_out;

    k_init<<<dim3(1), 128, 0, stream>>>(ws);
    k_fused<<<dim3(NBLK), 256, 0, stream>>>(clin, img, wself, wmsg, bg,
                                            W1, b1, W2, b2, ws, out);
}

// Round 4
// 175.424 us; speedup vs baseline: 2.9372x; 2.9372x over previous
//
#include <hip/hip_runtime.h>

#define FV 128
#define NCLIN 38
#define NPIX 36
#define NTOT 74     // NCLIN + NPIX
#define BATCH 1024
#define HID 512
#define COMB 4992   // 39*128 = 78*64
#define XPAD 136    // LDS row stride in ushorts

typedef __attribute__((ext_vector_type(4))) float f32x4;
typedef __attribute__((ext_vector_type(8))) short s16x8;

// ws layout (float offsets):
//   WcT bf16 [0, 8192)           (W_self + W_msg/37)^T, [n][k]
//   WiT bf16 [8192, 16384)       (W_self + W_msg/39)^T
//   WmT bf16 [16384, 24576)      W_msg^T  (for t-vector MFMA)
//   combined [24576, 2580480)    bf16 (1024 x 4992)
//   W1T      [2580480, 3858432)  bf16 (512 x 4992)
#define WS_WCT  0
#define WS_WIT  8192
#define WS_WMT  16384
#define WS_COMB 24576
#define WS_W1T  2580480

__device__ __forceinline__ unsigned short bf16_rne(float f) {
    union { float f; unsigned int u; } v; v.f = f;
    unsigned int u = v.u;
    u += 0x7fffu + ((u >> 16) & 1u);
    return (unsigned short)(u >> 16);
}
__device__ __forceinline__ float bf2f(unsigned short h) {
    union { unsigned int u; float f; } v; v.u = ((unsigned int)h) << 16;
    return v.f;
}

// Blocks 0..7: Wc/Wi/Wm transposed tables. Block 8: out[b] = b2[0] (head bias,
// GEMM kernel atomicAdds partials on top).
__global__ __launch_bounds__(256) void k_prep(
    const float* __restrict__ wself, const float* __restrict__ wmsg,
    const float* __restrict__ b2, float* __restrict__ ws,
    float* __restrict__ out)
{
    const int t = threadIdx.x;
    if (blockIdx.x == 8) {
        const float v = b2[0];
#pragma unroll
        for (int j = 0; j < 4; ++j) out[t + j * 256] = v;
        return;
    }
    unsigned short* WcT = (unsigned short*)(ws + WS_WCT);
    unsigned short* WiT = (unsigned short*)(ws + WS_WIT);
    unsigned short* WmT = (unsigned short*)(ws + WS_WMT);
    const int r  = blockIdx.x * 16 + (t >> 4);
    const int f0 = (t & 15) * 8;
#pragma unroll
    for (int j = 0; j < 8; ++j) {
        const int f = f0 + j;
        const int idx = r * 128 + f;
        const float wm = wmsg[idx];
        const float s  = wself[idx];
        WcT[f * 128 + r] = bf16_rne(s + wm * (1.0f / 37.0f));
        WiT[f * 128 + r] = bf16_rne(s + wm * (1.0f / 39.0f));
        WmT[f * 128 + r] = bf16_rne(wm);
    }
}

union __align__(16) SmemMain {
    float tile[64][65];                        // W1 transpose staging
    struct {
        unsigned short xl[NTOT * XPAD];
        unsigned short sab[2 * 128];
        float tcv[128];
        float tiv[128];
    } b;                                       // per-batch pipeline
};

// Blocks 0..1023: per-batch GNN pipeline -> combined.
// Blocks 1024..1647: W1 -> W1T bf16 transpose (independent; overlaps batch work).
__global__ __launch_bounds__(256) void k_main(
    const float* __restrict__ clin, const float* __restrict__ img,
    const float* __restrict__ bg, const float* __restrict__ W1,
    float* __restrict__ ws)
{
    const int blk = blockIdx.x;
    const int t   = threadIdx.x;
    __shared__ SmemMain sm;

    if (blk >= BATCH) {
        // ---- W1T transpose tile ----
        const int u  = blk - BATCH;          // 0..623
        unsigned short* W1T = (unsigned short*)(ws + WS_W1T);
        const int k0 = (u >> 3) * 64;
        const int n0 = (u & 7) * 64;
        const int r16 = t >> 4;
        const int c4  = (t & 15) * 4;
#pragma unroll
        for (int p = 0; p < 4; ++p) {
            const int r = p * 16 + r16;
            const float4 v = *(const float4*)&W1[(size_t)(k0 + r) * HID + n0 + c4];
            sm.tile[r][c4 + 0] = v.x; sm.tile[r][c4 + 1] = v.y;
            sm.tile[r][c4 + 2] = v.z; sm.tile[r][c4 + 3] = v.w;
        }
        __syncthreads();
        const int j  = t >> 2;
        const int i0 = (t & 3) * 16;
        unsigned short tmp[16];
#pragma unroll
        for (int s = 0; s < 16; ++s) tmp[s] = bf16_rne(sm.tile[i0 + s][j]);
        unsigned short* dst = &W1T[(size_t)(n0 + j) * COMB + k0 + i0];
        *(uint4*)&dst[0] = *(uint4*)&tmp[0];
        *(uint4*)&dst[8] = *(uint4*)&tmp[8];
        return;
    }

    // ---- per-batch pipeline ----
    const unsigned short* WcT = (const unsigned short*)(ws + WS_WCT);
    const unsigned short* WiT = (const unsigned short*)(ws + WS_WIT);
    const unsigned short* WmT = (const unsigned short*)(ws + WS_WMT);
    const int wave = t >> 6;
    const int lane = t & 63;
    const int l16  = lane & 15;
    const int q    = lane >> 4;
    const int n0   = wave * 32 + l16;
    const int b    = blk;

    // stage x as bf16
    const float* xc = clin + (size_t)b * NCLIN * FV;
    const float* xi = img  + (size_t)b * NPIX * FV;
    for (int i = t; i < NCLIN * 32; i += 256) {
        const int row = i >> 5, c4 = (i & 31) * 4;
        const float4 v = *(const float4*)&xc[row * 128 + c4];
        ushort4 u;
        u.x = bf16_rne(v.x); u.y = bf16_rne(v.y);
        u.z = bf16_rne(v.z); u.w = bf16_rne(v.w);
        *(ushort4*)&sm.b.xl[row * XPAD + c4] = u;
    }
    for (int i = t; i < NPIX * 32; i += 256) {
        const int row = i >> 5, c4 = (i & 31) * 4;
        const float4 v = *(const float4*)&xi[row * 128 + c4];
        ushort4 u;
        u.x = bf16_rne(v.x); u.y = bf16_rne(v.y);
        u.z = bf16_rne(v.z); u.w = bf16_rne(v.w);
        *(ushort4*)&sm.b.xl[(NCLIN + row) * XPAD + c4] = u;
    }
    __syncthreads();

    // feature sums -> sab (bf16)
    const int f = t & 127;
    if (t < 128) {
        float s = 0.f;
#pragma unroll
        for (int n = 0; n < NCLIN; ++n) s += bf2f(sm.b.xl[n * XPAD + f]);
        sm.b.sab[128 + f] = bf16_rne(s * (1.0f / 39.0f));
    } else {
        float s = 0.f;
#pragma unroll
        for (int n = 0; n < NPIX; ++n) s += bf2f(sm.b.xl[(NCLIN + n) * XPAD + f]);
        sm.b.sab[f] = bf16_rne(s * (1.0f / 37.0f));
    }
    __syncthreads();

    // t vectors via MFMA
    {
        const int am = (l16 < 2) ? l16 : 0;
        f32x4 ta = {}, tb = {};
#pragma unroll
        for (int kk = 0; kk < 4; ++kk) {
            const int ko = kk * 32 + q * 8;
            const s16x8 av  = *(const s16x8*)&sm.b.sab[am * 128 + ko];
            const s16x8 bv0 = *(const s16x8*)&WmT[(n0)      * 128 + ko];
            const s16x8 bv1 = *(const s16x8*)&WmT[(n0 + 16) * 128 + ko];
            ta = __builtin_amdgcn_mfma_f32_16x16x32_bf16(av, bv0, ta, 0, 0, 0);
            tb = __builtin_amdgcn_mfma_f32_16x16x32_bf16(av, bv1, tb, 0, 0, 0);
        }
        if (q == 0) {
            const int c0 = wave * 32 + l16;
            const int c1 = c0 + 16;
            const float bg0 = bg[c0], bg1 = bg[c1];
            sm.b.tcv[c0] = ta[0] + bg0;  sm.b.tiv[c0] = ta[1] + bg0;
            sm.b.tcv[c1] = tb[0] + bg1;  sm.b.tiv[c1] = tb[1] + bg1;
        }
    }
    __syncthreads();

    // MFMA node transform, both phases
    unsigned short* combined =
        (unsigned short*)(ws + WS_COMB) + (size_t)b * COMB;

#pragma unroll
    for (int phase = 0; phase < 2; ++phase) {
        const int NN   = phase ? NPIX : NCLIN;
        const int xoff = phase ? NCLIN : 0;
        const unsigned short* WT = phase ? WiT : WcT;
        const float* tvv = phase ? sm.b.tiv : sm.b.tcv;

        const int r0 = xoff + ((l16      < NN) ? l16      : (NN - 1));
        const int r1 = xoff + ((16 + l16 < NN) ? 16 + l16 : (NN - 1));
        const int r2 = xoff + ((32 + l16 < NN) ? 32 + l16 : (NN - 1));

        f32x4 acc[3][2] = {};
#pragma unroll
        for (int kk = 0; kk < 4; ++kk) {
            const int ko = kk * 32 + q * 8;
            const s16x8 a0 = *(const s16x8*)&sm.b.xl[r0 * XPAD + ko];
            const s16x8 a1 = *(const s16x8*)&sm.b.xl[r1 * XPAD + ko];
            const s16x8 a2 = *(const s16x8*)&sm.b.xl[r2 * XPAD + ko];
            const s16x8 b0 = *(const s16x8*)&WT[(n0)      * 128 + ko];
            const s16x8 b1v = *(const s16x8*)&WT[(n0 + 16) * 128 + ko];
            acc[0][0] = __builtin_amdgcn_mfma_f32_16x16x32_bf16(a0, b0,  acc[0][0], 0, 0, 0);
            acc[0][1] = __builtin_amdgcn_mfma_f32_16x16x32_bf16(a0, b1v, acc[0][1], 0, 0, 0);
            acc[1][0] = __builtin_amdgcn_mfma_f32_16x16x32_bf16(a1, b0,  acc[1][0], 0, 0, 0);
            acc[1][1] = __builtin_amdgcn_mfma_f32_16x16x32_bf16(a1, b1v, acc[1][1], 0, 0, 0);
            acc[2][0] = __builtin_amdgcn_mfma_f32_16x16x32_bf16(a2, b0,  acc[2][0], 0, 0, 0);
            acc[2][1] = __builtin_amdgcn_mfma_f32_16x16x32_bf16(a2, b1v, acc[2][1], 0, 0, 0);
        }

        const float t0 = tvv[wave * 32 + l16];
        const float t1 = tvv[wave * 32 + 16 + l16];

        if (phase == 0) {
#pragma unroll
            for (int rt = 0; rt < 3; ++rt) {
#pragma unroll
                for (int r = 0; r < 4; ++r) {
                    const int node = rt * 16 + q * 4 + r;
                    if (node < NCLIN) {
                        combined[node * 128 + wave * 32 + l16] =
                            bf16_rne(fmaxf(acc[rt][0][r] + t0, 0.f));
                        combined[node * 128 + wave * 32 + 16 + l16] =
                            bf16_rne(fmaxf(acc[rt][1][r] + t1, 0.f));
                    }
                }
            }
        } else {
            float g0 = 0.f, g1 = 0.f;
#pragma unroll
            for (int rt = 0; rt < 3; ++rt) {
#pragma unroll
                for (int r = 0; r < 4; ++r) {
                    const int node = rt * 16 + q * 4 + r;
                    if (node < NPIX) {
                        g0 += fmaxf(acc[rt][0][r] + t0, 0.f);
                        g1 += fmaxf(acc[rt][1][r] + t1, 0.f);
                    }
                }
            }
            g0 += __shfl_xor(g0, 16); g0 += __shfl_xor(g0, 32);
            g1 += __shfl_xor(g1, 16); g1 += __shfl_xor(g1, 32);
            if (q == 0) {
                combined[NCLIN * 128 + wave * 32 + l16] =
                    bf16_rne(g0 * (1.0f / 36.0f));
                combined[NCLIN * 128 + wave * 32 + 16 + l16] =
                    bf16_rne(g1 * (1.0f / 36.0f));
            }
        }
    }
}

// Full-K GEMM tile (64m x 64n, BK=64) + fused head epilogue:
// v = relu(z + b1) * W2, reduced over the tile's 64 columns, atomicAdd into out.
// Grid 16m x 8n = 128 blocks. Chunk-rotation swizzle (chunk'=(chunk+row)&7 on
// 16B granules within each 128B row) -> balanced 8-lane/16B-slot on both
// ds_write_b128 and ds_read_b128 (the b128 minimum = conflict-free).
__global__ __launch_bounds__(256) void k_gemm_out(
    const float* __restrict__ b1, const float* __restrict__ W2,
    float* __restrict__ ws, float* __restrict__ out)
{
    const unsigned short* Abase = (const unsigned short*)(ws + WS_COMB);
    const unsigned short* Bbase = (const unsigned short*)(ws + WS_W1T);
    const int m0 = (blockIdx.x & 15) * 64;
    const int n0 = (blockIdx.x >> 4) * 64;

    __shared__ __align__(16) unsigned short As[2][64 * 64];  // 2 x 8 KB
    __shared__ __align__(16) unsigned short Bs[2][64 * 64];  // 2 x 8 KB

    const int t    = threadIdx.x;
    const int wave = t >> 6;
    const int lane = t & 63;
    const int wm   = (wave & 1) * 32;
    const int wn   = (wave >> 1) * 32;
    const int l16  = lane & 15;
    const int q    = lane >> 4;

    // staging: thread -> row = t>>2 (0..63), chunk pair c0 = (t&3)*2
    const int srow = t >> 2;
    const int c0   = (t & 3) * 2;
    const unsigned short* gA = Abase + (size_t)(m0 + srow) * COMB + c0 * 8;
    const unsigned short* gB = Bbase + (size_t)(n0 + srow) * COMB + c0 * 8;
    const int sw0 = srow * 64 + ((c0     + srow) & 7) * 8;
    const int sw1 = srow * 64 + ((c0 + 1 + srow) & 7) * 8;

    // per-lane swizzled read offsets: [frag i][k-step kk]
    int aoff[2][2], boff[2][2];
#pragma unroll
    for (int i = 0; i < 2; ++i) {
#pragma unroll
        for (int kk = 0; kk < 2; ++kk) {
            const int rot = (kk * 4 + q + l16) & 7;   // (row&7)==l16&7 within 16-row step
            aoff[i][kk] = (wm + 16 * i + l16) * 64 + rot * 8;
            boff[i][kk] = (wn + 16 * i + l16) * 64 + rot * 8;
        }
    }

    f32x4 acc[2][2] = {};

    // prologue: stage tile 0 into buf 0
    *(uint4*)&As[0][sw0] = *(const uint4*)(gA);
    *(uint4*)&As[0][sw1] = *(const uint4*)(gA + 8);
    *(uint4*)&Bs[0][sw0] = *(const uint4*)(gB);
    *(uint4*)&Bs[0][sw1] = *(const uint4*)(gB + 8);

    int cur = 0;
    for (int it = 0; it < 78; ++it) {
        __syncthreads();   // buf[cur] staged; buf[cur^1] reads (it-1) complete
        if (it + 1 < 78) {
            const int kk  = (it + 1) * 64;
            const int nxt = cur ^ 1;
            *(uint4*)&As[nxt][sw0] = *(const uint4*)(gA + kk);
            *(uint4*)&As[nxt][sw1] = *(const uint4*)(gA + kk + 8);
            *(uint4*)&Bs[nxt][sw0] = *(const uint4*)(gB + kk);
            *(uint4*)&Bs[nxt][sw1] = *(const uint4*)(gB + kk + 8);
        }

#pragma unroll
        for (int kk = 0; kk < 2; ++kk) {
            const s16x8 a0 = *(const s16x8*)&As[cur][aoff[0][kk]];
            const s16x8 a1 = *(const s16x8*)&As[cur][aoff[1][kk]];
            const s16x8 b0 = *(const s16x8*)&Bs[cur][boff[0][kk]];
            const s16x8 b1v = *(const s16x8*)&Bs[cur][boff[1][kk]];
            acc[0][0] = __builtin_amdgcn_mfma_f32_16x16x32_bf16(a0, b0,  acc[0][0], 0, 0, 0);
            acc[0][1] = __builtin_amdgcn_mfma_f32_16x16x32_bf16(a0, b1v, acc[0][1], 0, 0, 0);
            acc[1][0] = __builtin_amdgcn_mfma_f32_16x16x32_bf16(a1, b0,  acc[1][0], 0, 0, 0);
            acc[1][1] = __builtin_amdgcn_mfma_f32_16x16x32_bf16(a1, b1v, acc[1][1], 0, 0, 0);
        }
        cur ^= 1;
    }

    // epilogue: z -> relu(z + b1)*W2, reduce over this wave's 32 columns,
    // then cross-lane (l16) reduce and atomicAdd per row.
    const int colA = n0 + wn + l16;
    const int colB = colA + 16;
    const float b1a = b1[colA], b1b = b1[colB];
    const float w2a = W2[colA], w2b = W2[colB];

#pragma unroll
    for (int i = 0; i < 2; ++i) {
#pragma unroll
        for (int r = 0; r < 4; ++r) {
            const int mr = m0 + wm + 16 * i + q * 4 + r;
            float v = fmaxf(acc[i][0][r] + b1a, 0.f) * w2a
                    + fmaxf(acc[i][1][r] + b1b, 0.f) * w2b;
            v += __shfl_xor(v, 1);
            v += __shfl_xor(v, 2);
            v += __shfl_xor(v, 4);
            v += __shfl_xor(v, 8);
            if (l16 == 0) atomicAdd(&out[mr], v);
        }
    }
}

extern "C" void kernel_launch(void* const* d_in, const int* in_sizes, int n_in,
                              void* d_out, int out_size, void* d_ws, size_t ws_size,
                              hipStream_t stream) {
    const float* clin  = (const float*)d_in[0];
    const float* img   = (const float*)d_in[1];
    const float* wself = (const float*)d_in[2];
    const float* wmsg  = (const float*)d_in[3];
    const float* bg    = (const float*)d_in[4];
    const float* W1    = (const float*)d_in[5];
    const float* b1    = (const float*)d_in[6];
    const float* W2    = (const float*)d_in[7];
    const float* b2    = (const float*)d_in[8];
    float* ws  = (float*)d_ws;
    float* out = (float*)d_out;

    k_prep<<<dim3(9), 256, 0, stream>>>(wself, wmsg, b2, ws, out);
    k_main<<<dim3(BATCH + 624), 256, 0, stream>>>(clin, img, bg, W1, ws);
    k_gemm_out<<<dim3(128), 256, 0, stream>>>(b1, W2, ws, out);
}

// Round 5
// 144.388 us; speedup vs baseline: 3.5686x; 1.2150x over previous
//
#include <hip/hip_runtime.h>

#define FV 128
#define NCLIN 38
#define NPIX 36
#define NTOT 74     // NCLIN + NPIX
#define BATCH 1024
#define HID 512
#define COMB 4992   // 39*128 = 78*64
#define XPAD 136    // LDS row stride in ushorts

typedef __attribute__((ext_vector_type(4))) float f32x4;
typedef __attribute__((ext_vector_type(8))) short s16x8;

// ws layout (float offsets):
//   WcT bf16 [0, 8192)           (W_self + W_msg/37)^T, [n][k]
//   WiT bf16 [8192, 16384)       (W_self + W_msg/39)^T
//   WmT bf16 [16384, 24576)      W_msg^T  (for t-vector MFMA)
//   combined [24576, 2580480)    bf16 (1024 x 4992)
//   W1T      [2580480, 3858432)  bf16 (512 x 4992)
//   z[8]     [3858432, 8052736)  fp32 partials, 8 x (1024 x 512)
#define WS_WCT  0
#define WS_WIT  8192
#define WS_WMT  16384
#define WS_COMB 24576
#define WS_W1T  2580480
#define WS_Z    3858432
#define ZSTRIDE (BATCH * HID)

__device__ __forceinline__ unsigned short bf16_rne(float f) {
    union { float f; unsigned int u; } v; v.f = f;
    unsigned int u = v.u;
    u += 0x7fffu + ((u >> 16) & 1u);
    return (unsigned short)(u >> 16);
}
__device__ __forceinline__ float bf2f(unsigned short h) {
    union { unsigned int u; float f; } v; v.u = ((unsigned int)h) << 16;
    return v.f;
}

// Blocks 0..7: Wc/Wi/Wm transposed tables.
__global__ __launch_bounds__(256) void k_prep(
    const float* __restrict__ wself, const float* __restrict__ wmsg,
    float* __restrict__ ws)
{
    const int t = threadIdx.x;
    unsigned short* WcT = (unsigned short*)(ws + WS_WCT);
    unsigned short* WiT = (unsigned short*)(ws + WS_WIT);
    unsigned short* WmT = (unsigned short*)(ws + WS_WMT);
    const int r  = blockIdx.x * 16 + (t >> 4);
    const int f0 = (t & 15) * 8;
#pragma unroll
    for (int j = 0; j < 8; ++j) {
        const int f = f0 + j;
        const int idx = r * 128 + f;
        const float wm = wmsg[idx];
        const float s  = wself[idx];
        WcT[f * 128 + r] = bf16_rne(s + wm * (1.0f / 37.0f));
        WiT[f * 128 + r] = bf16_rne(s + wm * (1.0f / 39.0f));
        WmT[f * 128 + r] = bf16_rne(wm);
    }
}

union __align__(16) SmemMain {
    float tile[64][65];                        // W1 transpose staging
    struct {
        unsigned short xl[NTOT * XPAD];
        unsigned short sab[2 * 128];
        float tcv[128];
        float tiv[128];
    } b;                                       // per-batch pipeline
};

// Blocks 0..1023: per-batch GNN pipeline -> combined.
// Blocks 1024..1647: W1 -> W1T bf16 transpose (independent; overlaps batch work).
__global__ __launch_bounds__(256) void k_main(
    const float* __restrict__ clin, const float* __restrict__ img,
    const float* __restrict__ bg, const float* __restrict__ W1,
    float* __restrict__ ws)
{
    const int blk = blockIdx.x;
    const int t   = threadIdx.x;
    __shared__ SmemMain sm;

    if (blk >= BATCH) {
        // ---- W1T transpose tile ----
        const int u  = blk - BATCH;          // 0..623
        unsigned short* W1T = (unsigned short*)(ws + WS_W1T);
        const int k0 = (u >> 3) * 64;
        const int n0 = (u & 7) * 64;
        const int r16 = t >> 4;
        const int c4  = (t & 15) * 4;
#pragma unroll
        for (int p = 0; p < 4; ++p) {
            const int r = p * 16 + r16;
            const float4 v = *(const float4*)&W1[(size_t)(k0 + r) * HID + n0 + c4];
            sm.tile[r][c4 + 0] = v.x; sm.tile[r][c4 + 1] = v.y;
            sm.tile[r][c4 + 2] = v.z; sm.tile[r][c4 + 3] = v.w;
        }
        __syncthreads();
        const int j  = t >> 2;
        const int i0 = (t & 3) * 16;
        unsigned short tmp[16];
#pragma unroll
        for (int s = 0; s < 16; ++s) tmp[s] = bf16_rne(sm.tile[i0 + s][j]);
        unsigned short* dst = &W1T[(size_t)(n0 + j) * COMB + k0 + i0];
        *(uint4*)&dst[0] = *(uint4*)&tmp[0];
        *(uint4*)&dst[8] = *(uint4*)&tmp[8];
        return;
    }

    // ---- per-batch pipeline ----
    const unsigned short* WcT = (const unsigned short*)(ws + WS_WCT);
    const unsigned short* WiT = (const unsigned short*)(ws + WS_WIT);
    const unsigned short* WmT = (const unsigned short*)(ws + WS_WMT);
    const int wave = t >> 6;
    const int lane = t & 63;
    const int l16  = lane & 15;
    const int q    = lane >> 4;
    const int n0   = wave * 32 + l16;
    const int b    = blk;

    // stage x as bf16
    const float* xc = clin + (size_t)b * NCLIN * FV;
    const float* xi = img  + (size_t)b * NPIX * FV;
    for (int i = t; i < NCLIN * 32; i += 256) {
        const int row = i >> 5, c4 = (i & 31) * 4;
        const float4 v = *(const float4*)&xc[row * 128 + c4];
        ushort4 u;
        u.x = bf16_rne(v.x); u.y = bf16_rne(v.y);
        u.z = bf16_rne(v.z); u.w = bf16_rne(v.w);
        *(ushort4*)&sm.b.xl[row * XPAD + c4] = u;
    }
    for (int i = t; i < NPIX * 32; i += 256) {
        const int row = i >> 5, c4 = (i & 31) * 4;
        const float4 v = *(const float4*)&xi[row * 128 + c4];
        ushort4 u;
        u.x = bf16_rne(v.x); u.y = bf16_rne(v.y);
        u.z = bf16_rne(v.z); u.w = bf16_rne(v.w);
        *(ushort4*)&sm.b.xl[(NCLIN + row) * XPAD + c4] = u;
    }
    __syncthreads();

    // feature sums -> sab (bf16)
    const int f = t & 127;
    if (t < 128) {
        float s = 0.f;
#pragma unroll
        for (int n = 0; n < NCLIN; ++n) s += bf2f(sm.b.xl[n * XPAD + f]);
        sm.b.sab[128 + f] = bf16_rne(s * (1.0f / 39.0f));
    } else {
        float s = 0.f;
#pragma unroll
        for (int n = 0; n < NPIX; ++n) s += bf2f(sm.b.xl[(NCLIN + n) * XPAD + f]);
        sm.b.sab[f] = bf16_rne(s * (1.0f / 37.0f));
    }
    __syncthreads();

    // t vectors via MFMA
    {
        const int am = (l16 < 2) ? l16 : 0;
        f32x4 ta = {}, tb = {};
#pragma unroll
        for (int kk = 0; kk < 4; ++kk) {
            const int ko = kk * 32 + q * 8;
            const s16x8 av  = *(const s16x8*)&sm.b.sab[am * 128 + ko];
            const s16x8 bv0 = *(const s16x8*)&WmT[(n0)      * 128 + ko];
            const s16x8 bv1 = *(const s16x8*)&WmT[(n0 + 16) * 128 + ko];
            ta = __builtin_amdgcn_mfma_f32_16x16x32_bf16(av, bv0, ta, 0, 0, 0);
            tb = __builtin_amdgcn_mfma_f32_16x16x32_bf16(av, bv1, tb, 0, 0, 0);
        }
        if (q == 0) {
            const int c0 = wave * 32 + l16;
            const int c1 = c0 + 16;
            const float bg0 = bg[c0], bg1 = bg[c1];
            sm.b.tcv[c0] = ta[0] + bg0;  sm.b.tiv[c0] = ta[1] + bg0;
            sm.b.tcv[c1] = tb[0] + bg1;  sm.b.tiv[c1] = tb[1] + bg1;
        }
    }
    __syncthreads();

    // MFMA node transform, both phases
    unsigned short* combined =
        (unsigned short*)(ws + WS_COMB) + (size_t)b * COMB;

#pragma unroll
    for (int phase = 0; phase < 2; ++phase) {
        const int NN   = phase ? NPIX : NCLIN;
        const int xoff = phase ? NCLIN : 0;
        const unsigned short* WT = phase ? WiT : WcT;
        const float* tvv = phase ? sm.b.tiv : sm.b.tcv;

        const int r0 = xoff + ((l16      < NN) ? l16      : (NN - 1));
        const int r1 = xoff + ((16 + l16 < NN) ? 16 + l16 : (NN - 1));
        const int r2 = xoff + ((32 + l16 < NN) ? 32 + l16 : (NN - 1));

        f32x4 acc[3][2] = {};
#pragma unroll
        for (int kk = 0; kk < 4; ++kk) {
            const int ko = kk * 32 + q * 8;
            const s16x8 a0 = *(const s16x8*)&sm.b.xl[r0 * XPAD + ko];
            const s16x8 a1 = *(const s16x8*)&sm.b.xl[r1 * XPAD + ko];
            const s16x8 a2 = *(const s16x8*)&sm.b.xl[r2 * XPAD + ko];
            const s16x8 b0 = *(const s16x8*)&WT[(n0)      * 128 + ko];
            const s16x8 b1v = *(const s16x8*)&WT[(n0 + 16) * 128 + ko];
            acc[0][0] = __builtin_amdgcn_mfma_f32_16x16x32_bf16(a0, b0,  acc[0][0], 0, 0, 0);
            acc[0][1] = __builtin_amdgcn_mfma_f32_16x16x32_bf16(a0, b1v, acc[0][1], 0, 0, 0);
            acc[1][0] = __builtin_amdgcn_mfma_f32_16x16x32_bf16(a1, b0,  acc[1][0], 0, 0, 0);
            acc[1][1] = __builtin_amdgcn_mfma_f32_16x16x32_bf16(a1, b1v, acc[1][1], 0, 0, 0);
            acc[2][0] = __builtin_amdgcn_mfma_f32_16x16x32_bf16(a2, b0,  acc[2][0], 0, 0, 0);
            acc[2][1] = __builtin_amdgcn_mfma_f32_16x16x32_bf16(a2, b1v, acc[2][1], 0, 0, 0);
        }

        const float t0 = tvv[wave * 32 + l16];
        const float t1 = tvv[wave * 32 + 16 + l16];

        if (phase == 0) {
#pragma unroll
            for (int rt = 0; rt < 3; ++rt) {
#pragma unroll
                for (int r = 0; r < 4; ++r) {
                    const int node = rt * 16 + q * 4 + r;
                    if (node < NCLIN) {
                        combined[node * 128 + wave * 32 + l16] =
                            bf16_rne(fmaxf(acc[rt][0][r] + t0, 0.f));
                        combined[node * 128 + wave * 32 + 16 + l16] =
                            bf16_rne(fmaxf(acc[rt][1][r] + t1, 0.f));
                    }
                }
            }
        } else {
            float g0 = 0.f, g1 = 0.f;
#pragma unroll
            for (int rt = 0; rt < 3; ++rt) {
#pragma unroll
                for (int r = 0; r < 4; ++r) {
                    const int node = rt * 16 + q * 4 + r;
                    if (node < NPIX) {
                        g0 += fmaxf(acc[rt][0][r] + t0, 0.f);
                        g1 += fmaxf(acc[rt][1][r] + t1, 0.f);
                    }
                }
            }
            g0 += __shfl_xor(g0, 16); g0 += __shfl_xor(g0, 32);
            g1 += __shfl_xor(g1, 16); g1 += __shfl_xor(g1, 32);
            if (q == 0) {
                combined[NCLIN * 128 + wave * 32 + l16] =
                    bf16_rne(g0 * (1.0f / 36.0f));
                combined[NCLIN * 128 + wave * 32 + 16 + l16] =
                    bf16_rne(g1 * (1.0f / 36.0f));
            }
        }
    }
}

// z[ks] = combined[:, kslice] @ W1T[:, kslice]^T via bf16 MFMA.
// Block 64m x 128n, BK=64, waves 2x2 (each 32m x 64n). Split-K=8 uneven
// (6x640 + 2x576). Grid (16,4,8) = 512 blocks = 2/CU.
// T14 async-STAGE: global loads for tile it+2 issued at iter it into regs;
// ds_write of tile it+1 (loaded a full iteration ago) right after the barrier,
// so the vmcnt wait there has ~1 iter + barrier of slack instead of zero.
// LDS chunk-rotation swizzle chunk'=(chunk+row)&7 on 16B granules: balanced
// 8 lanes/bank-group on ds_write_b128 and ds_read_b128 (the b128 minimum;
// verified conflict-free in round 4: SQ_LDS_BANK_CONFLICT = 0).
__global__ __launch_bounds__(256) void k_gemm_mfma(float* __restrict__ ws)
{
    const unsigned short* Abase = (const unsigned short*)(ws + WS_COMB);
    const unsigned short* Bbase = (const unsigned short*)(ws + WS_W1T);
    const int m0    = blockIdx.x * 64;
    const int n0    = blockIdx.y * 128;
    const int ks    = blockIdx.z;
    const int kbase = (ks < 6) ? 640 * ks : 3840 + 576 * (ks - 6);
    const int kit   = (ks < 6) ? 10 : 9;
    float* Z = ws + WS_Z + (size_t)ks * ZSTRIDE;

    __shared__ __align__(16) unsigned short As[2][64 * 64];   // 2 x 8 KB
    __shared__ __align__(16) unsigned short Bs[2][128 * 64];  // 2 x 16 KB

    const int t    = threadIdx.x;
    const int wave = t >> 6;
    const int lane = t & 63;
    const int wm   = (wave & 1) * 32;
    const int wn   = (wave >> 1) * 64;
    const int l16  = lane & 15;
    const int q    = lane >> 4;

    // staging map: A row = t>>2 (64 rows), chunks (t&3)*2 and +1;
    //              B row = t>>1 (128 rows), chunks (t&1)*4 .. +3
    const int arow = t >> 2;
    const int ac0  = (t & 3) * 2;
    const int brow = t >> 1;
    const int bc0  = (t & 1) * 4;
    const unsigned short* gA = Abase + (size_t)(m0 + arow) * COMB + kbase + ac0 * 8;
    const unsigned short* gB = Bbase + (size_t)(n0 + brow) * COMB + kbase + bc0 * 8;

    const int awo0 = arow * 64 + ((ac0     + arow) & 7) * 8;
    const int awo1 = arow * 64 + ((ac0 + 1 + arow) & 7) * 8;
    int bwo[4];
#pragma unroll
    for (int j = 0; j < 4; ++j)
        bwo[j] = brow * 64 + ((bc0 + j + brow) & 7) * 8;

    // read offsets: A rows wm+16i+l16, B rows wn+16j+l16, k-chunk kk*4+q
    int aoff[2][2], boff[4][2];
#pragma unroll
    for (int kk = 0; kk < 2; ++kk) {
#pragma unroll
        for (int i = 0; i < 2; ++i) {
            const int Ra = wm + 16 * i + l16;
            aoff[i][kk] = Ra * 64 + ((kk * 4 + q + Ra) & 7) * 8;
        }
#pragma unroll
        for (int j = 0; j < 4; ++j) {
            const int Rb = wn + 16 * j + l16;
            boff[j][kk] = Rb * 64 + ((kk * 4 + q + Rb) & 7) * 8;
        }
    }

    f32x4 acc[2][4] = {};

    // pending-tile registers (tile it+1 during iter it)
    uint4 pA0, pA1, pB0, pB1, pB2, pB3;

    // prologue: tile 0 -> regs -> buf0; issue tile 1 -> regs
    pA0 = *(const uint4*)(gA);      pA1 = *(const uint4*)(gA + 8);
    pB0 = *(const uint4*)(gB);      pB1 = *(const uint4*)(gB + 8);
    pB2 = *(const uint4*)(gB + 16); pB3 = *(const uint4*)(gB + 24);
    *(uint4*)&As[0][awo0]   = pA0;  *(uint4*)&As[0][awo1]   = pA1;
    *(uint4*)&Bs[0][bwo[0]] = pB0;  *(uint4*)&Bs[0][bwo[1]] = pB1;
    *(uint4*)&Bs[0][bwo[2]] = pB2;  *(uint4*)&Bs[0][bwo[3]] = pB3;
    if (kit > 1) {
        pA0 = *(const uint4*)(gA + 64);      pA1 = *(const uint4*)(gA + 72);
        pB0 = *(const uint4*)(gB + 64);      pB1 = *(const uint4*)(gB + 72);
        pB2 = *(const uint4*)(gB + 80);      pB3 = *(const uint4*)(gB + 88);
    }

    int cur = 0;
    for (int it = 0; it < kit; ++it) {
        __syncthreads();   // buf[cur] holds tile it; buf[cur^1] free
        const int nxt = cur ^ 1;
        if (it + 1 < kit) {
            *(uint4*)&As[nxt][awo0]   = pA0;  *(uint4*)&As[nxt][awo1]   = pA1;
            *(uint4*)&Bs[nxt][bwo[0]] = pB0;  *(uint4*)&Bs[nxt][bwo[1]] = pB1;
            *(uint4*)&Bs[nxt][bwo[2]] = pB2;  *(uint4*)&Bs[nxt][bwo[3]] = pB3;
        }
        if (it + 2 < kit) {
            const int kk = (it + 2) * 64;
            pA0 = *(const uint4*)(gA + kk);      pA1 = *(const uint4*)(gA + kk + 8);
            pB0 = *(const uint4*)(gB + kk);      pB1 = *(const uint4*)(gB + kk + 8);
            pB2 = *(const uint4*)(gB + kk + 16); pB3 = *(const uint4*)(gB + kk + 24);
        }

#pragma unroll
        for (int kk = 0; kk < 2; ++kk) {
            const s16x8 a0 = *(const s16x8*)&As[cur][aoff[0][kk]];
            const s16x8 a1 = *(const s16x8*)&As[cur][aoff[1][kk]];
            const s16x8 b0 = *(const s16x8*)&Bs[cur][boff[0][kk]];
            const s16x8 b1 = *(const s16x8*)&Bs[cur][boff[1][kk]];
            const s16x8 b2 = *(const s16x8*)&Bs[cur][boff[2][kk]];
            const s16x8 b3 = *(const s16x8*)&Bs[cur][boff[3][kk]];
            acc[0][0] = __builtin_amdgcn_mfma_f32_16x16x32_bf16(a0, b0, acc[0][0], 0, 0, 0);
            acc[0][1] = __builtin_amdgcn_mfma_f32_16x16x32_bf16(a0, b1, acc[0][1], 0, 0, 0);
            acc[0][2] = __builtin_amdgcn_mfma_f32_16x16x32_bf16(a0, b2, acc[0][2], 0, 0, 0);
            acc[0][3] = __builtin_amdgcn_mfma_f32_16x16x32_bf16(a0, b3, acc[0][3], 0, 0, 0);
            acc[1][0] = __builtin_amdgcn_mfma_f32_16x16x32_bf16(a1, b0, acc[1][0], 0, 0, 0);
            acc[1][1] = __builtin_amdgcn_mfma_f32_16x16x32_bf16(a1, b1, acc[1][1], 0, 0, 0);
            acc[1][2] = __builtin_amdgcn_mfma_f32_16x16x32_bf16(a1, b2, acc[1][2], 0, 0, 0);
            acc[1][3] = __builtin_amdgcn_mfma_f32_16x16x32_bf16(a1, b3, acc[1][3], 0, 0, 0);
        }
        cur ^= 1;
    }

    // C/D: col = l16, row = q*4 + r
#pragma unroll
    for (int i = 0; i < 2; ++i) {
#pragma unroll
        for (int r = 0; r < 4; ++r) {
            const int mr = m0 + wm + 16 * i + q * 4 + r;
            float* zr = Z + (size_t)mr * HID + n0 + wn + l16;
#pragma unroll
            for (int j = 0; j < 4; ++j) {
                zr[16 * j] = acc[i][j][r];
            }
        }
    }
}

// 4 batches per block (one per wave).
__global__ __launch_bounds__(256) void k_out(
    const float* __restrict__ b1, const float* __restrict__ W2,
    const float* __restrict__ b2, const float* __restrict__ ws,
    float* __restrict__ out)
{
    const int b = blockIdx.x * 4 + (threadIdx.x >> 6);
    const int l = threadIdx.x & 63;
    const float* z = ws + WS_Z + (size_t)b * HID;
    float s = 0.f;
#pragma unroll
    for (int j = 0; j < 8; ++j) {
        const int h = l + j * 64;
        float acc = b1[h];
#pragma unroll
        for (int p = 0; p < 8; ++p) acc += z[(size_t)p * ZSTRIDE + h];
        acc = fmaxf(acc, 0.f);
        s += acc * W2[h];
    }
#pragma unroll
    for (int off = 32; off > 0; off >>= 1) s += __shfl_down(s, off);
    if (l == 0) out[b] = s + b2[0];
}

extern "C" void kernel_launch(void* const* d_in, const int* in_sizes, int n_in,
                              void* d_out, int out_size, void* d_ws, size_t ws_size,
                              hipStream_t stream) {
    const float* clin  = (const float*)d_in[0];
    const float* img   = (const float*)d_in[1];
    const float* wself = (const float*)d_in[2];
    const float* wmsg  = (const float*)d_in[3];
    const float* bg    = (const float*)d_in[4];
    const float* W1    = (const float*)d_in[5];
    const float* b1    = (const float*)d_in[6];
    const float* W2    = (const float*)d_in[7];
    const float* b2    = (const float*)d_in[8];
    float* ws  = (float*)d_ws;
    float* out = (float*)d_out;

    k_prep<<<dim3(8), 256, 0, stream>>>(wself, wmsg, ws);
    k_main<<<dim3(BATCH + 624), 256, 0, stream>>>(clin, img, bg, W1, ws);
    k_gemm_mfma<<<dim3(16, 4, 8), 256, 0, stream>>>(ws);
    k_out<<<dim3(BATCH / 4), 256, 0, stream>>>(b1, W2, b2, ws, out);
}

// Round 6
// 143.732 us; speedup vs baseline: 3.5849x; 1.0046x over previous
//
#include <hip/hip_runtime.h>

#define FV 128
#define NCLIN 38
#define NPIX 36
#define NTOT 74     // NCLIN + NPIX
#define BATCH 1024
#define HID 512
#define COMB 4992   // 39*128 = 78*64
#define XPAD 136    // LDS row stride in ushorts

typedef __attribute__((ext_vector_type(4))) float f32x4;
typedef __attribute__((ext_vector_type(8))) short s16x8;

// ws layout (float offsets):
//   WcT bf16 [0, 8192)           (W_self + W_msg/37)^T, [n][k]
//   WiT bf16 [8192, 16384)       (W_self + W_msg/39)^T
//   WmT bf16 [16384, 24576)      W_msg^T  (for t-vector MFMA)
//   combined [24576, 2580480)    bf16 (1024 x 4992)
//   W1T      [2580480, 3858432)  bf16 (512 x 4992)
//   z[8]     [3858432, 8052736)  fp32 partials, 8 x (1024 x 512)
#define WS_WCT  0
#define WS_WIT  8192
#define WS_WMT  16384
#define WS_COMB 24576
#define WS_W1T  2580480
#define WS_Z    3858432
#define ZSTRIDE (BATCH * HID)

__device__ __forceinline__ unsigned short bf16_rne(float f) {
    union { float f; unsigned int u; } v; v.f = f;
    unsigned int u = v.u;
    u += 0x7fffu + ((u >> 16) & 1u);
    return (unsigned short)(u >> 16);
}
__device__ __forceinline__ float bf2f(unsigned short h) {
    union { unsigned int u; float f; } v; v.u = ((unsigned int)h) << 16;
    return v.f;
}

// Blocks 0..7: Wc/Wi/Wm transposed tables.
__global__ __launch_bounds__(256) void k_prep(
    const float* __restrict__ wself, const float* __restrict__ wmsg,
    float* __restrict__ ws)
{
    const int t = threadIdx.x;
    unsigned short* WcT = (unsigned short*)(ws + WS_WCT);
    unsigned short* WiT = (unsigned short*)(ws + WS_WIT);
    unsigned short* WmT = (unsigned short*)(ws + WS_WMT);
    const int r  = blockIdx.x * 16 + (t >> 4);
    const int f0 = (t & 15) * 8;
#pragma unroll
    for (int j = 0; j < 8; ++j) {
        const int f = f0 + j;
        const int idx = r * 128 + f;
        const float wm = wmsg[idx];
        const float s  = wself[idx];
        WcT[f * 128 + r] = bf16_rne(s + wm * (1.0f / 37.0f));
        WiT[f * 128 + r] = bf16_rne(s + wm * (1.0f / 39.0f));
        WmT[f * 128 + r] = bf16_rne(wm);
    }
}

union __align__(16) SmemMain {
    float tile[64][65];                        // W1 transpose staging (16.6 KB)
    struct {
        unsigned short xl[NTOT * XPAD];        // 20.1 KB
        unsigned short sab[2 * 128];           // 0.5 KB
    } b;                                       // per-batch pipeline (20.6 KB)
};

// Blocks 0..1023: per-batch GNN pipeline -> combined.
// Blocks 1024..1647: W1 -> W1T bf16 transpose (independent; overlaps batch work).
// t-vectors are wave-local: kept in registers + __shfl, no LDS / no 3rd barrier.
__global__ __launch_bounds__(256) void k_main(
    const float* __restrict__ clin, const float* __restrict__ img,
    const float* __restrict__ bg, const float* __restrict__ W1,
    float* __restrict__ ws)
{
    const int blk = blockIdx.x;
    const int t   = threadIdx.x;
    __shared__ SmemMain sm;

    if (blk >= BATCH) {
        // ---- W1T transpose tile ----
        const int u  = blk - BATCH;          // 0..623
        unsigned short* W1T = (unsigned short*)(ws + WS_W1T);
        const int k0 = (u >> 3) * 64;
        const int n0 = (u & 7) * 64;
        const int r16 = t >> 4;
        const int c4  = (t & 15) * 4;
#pragma unroll
        for (int p = 0; p < 4; ++p) {
            const int r = p * 16 + r16;
            const float4 v = *(const float4*)&W1[(size_t)(k0 + r) * HID + n0 + c4];
            sm.tile[r][c4 + 0] = v.x; sm.tile[r][c4 + 1] = v.y;
            sm.tile[r][c4 + 2] = v.z; sm.tile[r][c4 + 3] = v.w;
        }
        __syncthreads();
        const int j  = t >> 2;
        const int i0 = (t & 3) * 16;
        unsigned short tmp[16];
#pragma unroll
        for (int s = 0; s < 16; ++s) tmp[s] = bf16_rne(sm.tile[i0 + s][j]);
        unsigned short* dst = &W1T[(size_t)(n0 + j) * COMB + k0 + i0];
        *(uint4*)&dst[0] = *(uint4*)&tmp[0];
        *(uint4*)&dst[8] = *(uint4*)&tmp[8];
        return;
    }

    // ---- per-batch pipeline ----
    const unsigned short* WcT = (const unsigned short*)(ws + WS_WCT);
    const unsigned short* WiT = (const unsigned short*)(ws + WS_WIT);
    const unsigned short* WmT = (const unsigned short*)(ws + WS_WMT);
    const int wave = t >> 6;
    const int lane = t & 63;
    const int l16  = lane & 15;
    const int q    = lane >> 4;
    const int n0   = wave * 32 + l16;
    const int b    = blk;

    // stage x as bf16
    const float* xc = clin + (size_t)b * NCLIN * FV;
    const float* xi = img  + (size_t)b * NPIX * FV;
    for (int i = t; i < NCLIN * 32; i += 256) {
        const int row = i >> 5, c4 = (i & 31) * 4;
        const float4 v = *(const float4*)&xc[row * 128 + c4];
        ushort4 u;
        u.x = bf16_rne(v.x); u.y = bf16_rne(v.y);
        u.z = bf16_rne(v.z); u.w = bf16_rne(v.w);
        *(ushort4*)&sm.b.xl[row * XPAD + c4] = u;
    }
    for (int i = t; i < NPIX * 32; i += 256) {
        const int row = i >> 5, c4 = (i & 31) * 4;
        const float4 v = *(const float4*)&xi[row * 128 + c4];
        ushort4 u;
        u.x = bf16_rne(v.x); u.y = bf16_rne(v.y);
        u.z = bf16_rne(v.z); u.w = bf16_rne(v.w);
        *(ushort4*)&sm.b.xl[(NCLIN + row) * XPAD + c4] = u;
    }
    __syncthreads();

    // feature sums -> sab (bf16)
    const int f = t & 127;
    if (t < 128) {
        float s = 0.f;
#pragma unroll
        for (int n = 0; n < NCLIN; ++n) s += bf2f(sm.b.xl[n * XPAD + f]);
        sm.b.sab[128 + f] = bf16_rne(s * (1.0f / 39.0f));
    } else {
        float s = 0.f;
#pragma unroll
        for (int n = 0; n < NPIX; ++n) s += bf2f(sm.b.xl[(NCLIN + n) * XPAD + f]);
        sm.b.sab[f] = bf16_rne(s * (1.0f / 37.0f));
    }
    __syncthreads();

    // t vectors via MFMA: wave-local, results distributed by shfl (no barrier).
    float tc0, tc1, ti0, ti1;
    {
        const int am = (l16 < 2) ? l16 : 0;
        f32x4 ta = {}, tb = {};
#pragma unroll
        for (int kk = 0; kk < 4; ++kk) {
            const int ko = kk * 32 + q * 8;
            const s16x8 av  = *(const s16x8*)&sm.b.sab[am * 128 + ko];
            const s16x8 bv0 = *(const s16x8*)&WmT[(n0)      * 128 + ko];
            const s16x8 bv1 = *(const s16x8*)&WmT[(n0 + 16) * 128 + ko];
            ta = __builtin_amdgcn_mfma_f32_16x16x32_bf16(av, bv0, ta, 0, 0, 0);
            tb = __builtin_amdgcn_mfma_f32_16x16x32_bf16(av, bv1, tb, 0, 0, 0);
        }
        // valid rows live in q==0 lanes; source lane l16 has q==0.
        const float bgA = bg[wave * 32 + l16];
        const float bgB = bg[wave * 32 + 16 + l16];
        tc0 = __shfl(ta[0], l16) + bgA;   // clin t, col wave*32+l16
        tc1 = __shfl(tb[0], l16) + bgB;   // clin t, col +16
        ti0 = __shfl(ta[1], l16) + bgA;   // img t
        ti1 = __shfl(tb[1], l16) + bgB;
    }

    // MFMA node transform, both phases
    unsigned short* combined =
        (unsigned short*)(ws + WS_COMB) + (size_t)b * COMB;

#pragma unroll
    for (int phase = 0; phase < 2; ++phase) {
        const int NN   = phase ? NPIX : NCLIN;
        const int xoff = phase ? NCLIN : 0;
        const unsigned short* WT = phase ? WiT : WcT;

        const int r0 = xoff + ((l16      < NN) ? l16      : (NN - 1));
        const int r1 = xoff + ((16 + l16 < NN) ? 16 + l16 : (NN - 1));
        const int r2 = xoff + ((32 + l16 < NN) ? 32 + l16 : (NN - 1));

        f32x4 acc[3][2] = {};
#pragma unroll
        for (int kk = 0; kk < 4; ++kk) {
            const int ko = kk * 32 + q * 8;
            const s16x8 a0 = *(const s16x8*)&sm.b.xl[r0 * XPAD + ko];
            const s16x8 a1 = *(const s16x8*)&sm.b.xl[r1 * XPAD + ko];
            const s16x8 a2 = *(const s16x8*)&sm.b.xl[r2 * XPAD + ko];
            const s16x8 b0 = *(const s16x8*)&WT[(n0)      * 128 + ko];
            const s16x8 b1v = *(const s16x8*)&WT[(n0 + 16) * 128 + ko];
            acc[0][0] = __builtin_amdgcn_mfma_f32_16x16x32_bf16(a0, b0,  acc[0][0], 0, 0, 0);
            acc[0][1] = __builtin_amdgcn_mfma_f32_16x16x32_bf16(a0, b1v, acc[0][1], 0, 0, 0);
            acc[1][0] = __builtin_amdgcn_mfma_f32_16x16x32_bf16(a1, b0,  acc[1][0], 0, 0, 0);
            acc[1][1] = __builtin_amdgcn_mfma_f32_16x16x32_bf16(a1, b1v, acc[1][1], 0, 0, 0);
            acc[2][0] = __builtin_amdgcn_mfma_f32_16x16x32_bf16(a2, b0,  acc[2][0], 0, 0, 0);
            acc[2][1] = __builtin_amdgcn_mfma_f32_16x16x32_bf16(a2, b1v, acc[2][1], 0, 0, 0);
        }

        const float t0 = phase ? ti0 : tc0;
        const float t1 = phase ? ti1 : tc1;

        if (phase == 0) {
#pragma unroll
            for (int rt = 0; rt < 3; ++rt) {
#pragma unroll
                for (int r = 0; r < 4; ++r) {
                    const int node = rt * 16 + q * 4 + r;
                    if (node < NCLIN) {
                        combined[node * 128 + wave * 32 + l16] =
                            bf16_rne(fmaxf(acc[rt][0][r] + t0, 0.f));
                        combined[node * 128 + wave * 32 + 16 + l16] =
                            bf16_rne(fmaxf(acc[rt][1][r] + t1, 0.f));
                    }
                }
            }
        } else {
            float g0 = 0.f, g1 = 0.f;
#pragma unroll
            for (int rt = 0; rt < 3; ++rt) {
#pragma unroll
                for (int r = 0; r < 4; ++r) {
                    const int node = rt * 16 + q * 4 + r;
                    if (node < NPIX) {
                        g0 += fmaxf(acc[rt][0][r] + t0, 0.f);
                        g1 += fmaxf(acc[rt][1][r] + t1, 0.f);
                    }
                }
            }
            g0 += __shfl_xor(g0, 16); g0 += __shfl_xor(g0, 32);
            g1 += __shfl_xor(g1, 16); g1 += __shfl_xor(g1, 32);
            if (q == 0) {
                combined[NCLIN * 128 + wave * 32 + l16] =
                    bf16_rne(g0 * (1.0f / 36.0f));
                combined[NCLIN * 128 + wave * 32 + 16 + l16] =
                    bf16_rne(g1 * (1.0f / 36.0f));
            }
        }
    }
}

// z[ks] = combined[:, kslice] @ W1T[:, kslice]^T via bf16 MFMA.
// Block 64m x 64n, BK=64, waves 2x2 (each 32m x 32n). Split-K=8 uneven
// (6x640 + 2x576). Grid (16,8,8) = 1024 blocks; 32 KB LDS -> 4 blocks/CU
// resident (double the round-5 pool for latency hiding).
// T14 async-STAGE: tile it+2 global->regs at iter it; ds_write of tile it+1
// right after the barrier (vmcnt slack ~= 1 full iter). Chunk-rotation
// swizzle chunk'=(chunk+row)&7 on 16B granules (round-4 verified: 0 conflicts).
__global__ __launch_bounds__(256) void k_gemm_mfma(float* __restrict__ ws)
{
    const unsigned short* Abase = (const unsigned short*)(ws + WS_COMB);
    const unsigned short* Bbase = (const unsigned short*)(ws + WS_W1T);
    const int m0    = blockIdx.x * 64;
    const int n0    = blockIdx.y * 64;
    const int ks    = blockIdx.z;
    const int kbase = (ks < 6) ? 640 * ks : 3840 + 576 * (ks - 6);
    const int kit   = (ks < 6) ? 10 : 9;
    float* Z = ws + WS_Z + (size_t)ks * ZSTRIDE;

    __shared__ __align__(16) unsigned short As[2][64 * 64];  // 2 x 8 KB
    __shared__ __align__(16) unsigned short Bs[2][64 * 64];  // 2 x 8 KB

    const int t    = threadIdx.x;
    const int wave = t >> 6;
    const int lane = t & 63;
    const int wm   = (wave & 1) * 32;
    const int wn   = (wave >> 1) * 32;
    const int l16  = lane & 15;
    const int q    = lane >> 4;

    // staging map: row = t>>2 (0..63), chunk pair c0 = (t&3)*2
    const int srow = t >> 2;
    const int c0   = (t & 3) * 2;
    const unsigned short* gA = Abase + (size_t)(m0 + srow) * COMB + kbase + c0 * 8;
    const unsigned short* gB = Bbase + (size_t)(n0 + srow) * COMB + kbase + c0 * 8;
    const int sw0 = srow * 64 + ((c0     + srow) & 7) * 8;
    const int sw1 = srow * 64 + ((c0 + 1 + srow) & 7) * 8;

    // read offsets: A rows wm+16i+l16, B rows wn+16j+l16, chunk (kk*4+q+row)&7
    int aoff[2][2], boff[2][2];
#pragma unroll
    for (int kk = 0; kk < 2; ++kk) {
#pragma unroll
        for (int i = 0; i < 2; ++i) {
            const int Ra = wm + 16 * i + l16;
            aoff[i][kk] = Ra * 64 + ((kk * 4 + q + Ra) & 7) * 8;
            const int Rb = wn + 16 * i + l16;
            boff[i][kk] = Rb * 64 + ((kk * 4 + q + Rb) & 7) * 8;
        }
    }

    f32x4 acc[2][2] = {};

    // pending-tile registers (tile it+1 during iter it)
    uint4 pA0, pA1, pB0, pB1;

    // prologue: tile 0 -> regs -> buf0; issue tile 1 -> regs
    pA0 = *(const uint4*)(gA);     pA1 = *(const uint4*)(gA + 8);
    pB0 = *(const uint4*)(gB);     pB1 = *(const uint4*)(gB + 8);
    *(uint4*)&As[0][sw0] = pA0;    *(uint4*)&As[0][sw1] = pA1;
    *(uint4*)&Bs[0][sw0] = pB0;    *(uint4*)&Bs[0][sw1] = pB1;
    if (kit > 1) {
        pA0 = *(const uint4*)(gA + 64);  pA1 = *(const uint4*)(gA + 72);
        pB0 = *(const uint4*)(gB + 64);  pB1 = *(const uint4*)(gB + 72);
    }

    int cur = 0;
    for (int it = 0; it < kit; ++it) {
        __syncthreads();   // buf[cur] holds tile it; buf[cur^1] free
        const int nxt = cur ^ 1;
        if (it + 1 < kit) {
            *(uint4*)&As[nxt][sw0] = pA0;  *(uint4*)&As[nxt][sw1] = pA1;
            *(uint4*)&Bs[nxt][sw0] = pB0;  *(uint4*)&Bs[nxt][sw1] = pB1;
        }
        if (it + 2 < kit) {
            const int kk = (it + 2) * 64;
            pA0 = *(const uint4*)(gA + kk);  pA1 = *(const uint4*)(gA + kk + 8);
            pB0 = *(const uint4*)(gB + kk);  pB1 = *(const uint4*)(gB + kk + 8);
        }

#pragma unroll
        for (int kk = 0; kk < 2; ++kk) {
            const s16x8 a0 = *(const s16x8*)&As[cur][aoff[0][kk]];
            const s16x8 a1 = *(const s16x8*)&As[cur][aoff[1][kk]];
            const s16x8 b0 = *(const s16x8*)&Bs[cur][boff[0][kk]];
            const s16x8 b1 = *(const s16x8*)&Bs[cur][boff[1][kk]];
            acc[0][0] = __builtin_amdgcn_mfma_f32_16x16x32_bf16(a0, b0, acc[0][0], 0, 0, 0);
            acc[0][1] = __builtin_amdgcn_mfma_f32_16x16x32_bf16(a0, b1, acc[0][1], 0, 0, 0);
            acc[1][0] = __builtin_amdgcn_mfma_f32_16x16x32_bf16(a1, b0, acc[1][0], 0, 0, 0);
            acc[1][1] = __builtin_amdgcn_mfma_f32_16x16x32_bf16(a1, b1, acc[1][1], 0, 0, 0);
        }
        cur ^= 1;
    }

    // C/D: col = l16, row = q*4 + r
#pragma unroll
    for (int i = 0; i < 2; ++i) {
#pragma unroll
        for (int r = 0; r < 4; ++r) {
            const int mr = m0 + wm + 16 * i + q * 4 + r;
            float* zr = Z + (size_t)mr * HID + n0 + wn + l16;
#pragma unroll
            for (int j = 0; j < 2; ++j) {
                zr[16 * j] = acc[i][j][r];
            }
        }
    }
}

// 4 batches per block (one per wave).
__global__ __launch_bounds__(256) void k_out(
    const float* __restrict__ b1, const float* __restrict__ W2,
    const float* __restrict__ b2, const float* __restrict__ ws,
    float* __restrict__ out)
{
    const int b = blockIdx.x * 4 + (threadIdx.x >> 6);
    const int l = threadIdx.x & 63;
    const float* z = ws + WS_Z + (size_t)b * HID;
    float s = 0.f;
#pragma unroll
    for (int j = 0; j < 8; ++j) {
        const int h = l + j * 64;
        float acc = b1[h];
#pragma unroll
        for (int p = 0; p < 8; ++p) acc += z[(size_t)p * ZSTRIDE + h];
        acc = fmaxf(acc, 0.f);
        s += acc * W2[h];
    }
#pragma unroll
    for (int off = 32; off > 0; off >>= 1) s += __shfl_down(s, off);
    if (l == 0) out[b] = s + b2[0];
}

extern "C" void kernel_launch(void* const* d_in, const int* in_sizes, int n_in,
                              void* d_out, int out_size, void* d_ws, size_t ws_size,
                              hipStream_t stream) {
    const float* clin  = (const float*)d_in[0];
    const float* img   = (const float*)d_in[1];
    const float* wself = (const float*)d_in[2];
    const float* wmsg  = (const float*)d_in[3];
    const float* bg    = (const float*)d_in[4];
    const float* W1    = (const float*)d_in[5];
    const float* b1    = (const float*)d_in[6];
    const float* W2    = (const float*)d_in[7];
    const float* b2    = (const float*)d_in[8];
    float* ws  = (float*)d_ws;
    float* out = (float*)d_out;

    k_prep<<<dim3(8), 256, 0, stream>>>(wself, wmsg, ws);
    k_main<<<dim3(BATCH + 624), 256, 0, stream>>>(clin, img, bg, W1, ws);
    k_gemm_mfma<<<dim3(16, 8, 8), 256, 0, stream>>>(ws);
    k_out<<<dim3(BATCH / 4), 256, 0, stream>>>(b1, W2, b2, ws, out);
}